// Round 5
// baseline (2020.661 us; speedup 1.0000x reference)
//
#include <hip/hip_runtime.h>
#include <stdint.h>

// PointerNet fused forward. B=512, S=50, E=H=128.
// 512 blocks x 128 threads, 1 batch element per block. Thread i owns hidden
// unit i; LSTM cell state c stays in a register across all 100 steps.
// RG/RP live in LDS (stride 132), fused with the encoder. ws holds only
// packed weights (1.31 MB), rewritten with identical values every call.
//
// Round-5 hardening: ALL cross-lane communication is either (a) LDS write ->
// __syncthreads -> read, or (b) pure register shuffles. The round-3/4 in-wave
// LDS broadcast (sh_w -> lane-0 sum -> sh_red -> all-lane read, no barrier)
// was the only unprotected communication and the prime suspect for the
// replay-only tour divergence; it is replaced by an all-lane __shfl
// sequential sum (bit-identical order, no LDS).
//
// Dot products accumulate in f64 (single rounding to f32); elementwise math
// replicates XLA CPU bit patterns (tanh rational poly, logistic-as-tanh,
// sequential softmax sum). Sampling replicates jax.random.categorical with
// THREEFRY PARTITIONABLE mode (JAX >= 0.5 default):
//   fold_in: key' = tf2x32(key, (0, t))
//   split (foldlike): k1 = tf2x32(key', (0, 0))   [both output words]
//   random_bits(32): bits[j] = o0 ^ o1 of tf2x32(k1, (0, j))
// uniform->gumbel exactly as jax._src.random; argmax with first-index ties.

#define OFF_PIH_E 0
#define OFF_PHH_E 65536
#define OFF_PIH_D 131072
#define OFF_PHH_D 196608
#define OFF_PQG   262144
#define OFF_PRG   278528
#define OFF_PQP   294912
#define OFF_PRP   311296
// ws total: 327680 floats = 1.31 MB

#define RSTR 132   // LDS row stride for RG/RP (16B-aligned, caps conflicts)

#define TINYF 1.1754943508222875e-38f

static __device__ __forceinline__ float f_add(float a, float b){ return __fadd_rn(a,b); }
static __device__ __forceinline__ float f_mul(float a, float b){ return __fmul_rn(a,b); }
static __device__ __forceinline__ float f_sub(float a, float b){ return __fsub_rn(a,b); }

// XLA CPU tanh: elemental_ir_emitter rational approximation, unfused mul/add.
static __device__ __forceinline__ float tanh_xla(float x) {
  float xc = fminf(fmaxf(x, -7.90531110763549805f), 7.90531110763549805f);
  float x2 = f_mul(xc, xc);
  float p;
  p = -2.76076847742355e-16f;
  p = f_add(f_mul(p, x2),  2.00018790482477e-13f);
  p = f_add(f_mul(p, x2), -8.60467152213735e-11f);
  p = f_add(f_mul(p, x2),  5.12229709037114e-08f);
  p = f_add(f_mul(p, x2),  1.48572235717979e-05f);
  p = f_add(f_mul(p, x2),  6.37261928875436e-04f);
  p = f_add(f_mul(p, x2),  4.89352455891786e-03f);
  p = f_mul(xc, p);
  float q;
  q = 1.19825839466702e-06f;
  q = f_add(f_mul(q, x2), 1.18534705686654e-04f);
  q = f_add(f_mul(q, x2), 2.26843463243900e-03f);
  q = f_add(f_mul(q, x2), 4.89352518554385e-03f);
  float r = __fdiv_rn(p, q);
  return (fabsf(x) < 0.0004f) ? x : r;
}

// XLA logistic expansion: 0.5 + 0.5*tanh(0.5*x)
static __device__ __forceinline__ float sigmoid_xla(float x) {
  return f_add(0.5f, f_mul(0.5f, tanh_xla(f_mul(0.5f, x))));
}

// Threefry-2x32, 20 rounds (JAX key schedule)
static __device__ __forceinline__ void tf2x32(uint32_t k0, uint32_t k1,
                                              uint32_t x0, uint32_t x1,
                                              uint32_t &o0, uint32_t &o1) {
  uint32_t ks2 = k0 ^ k1 ^ 0x1BD11BDAu;
  x0 += k0; x1 += k1;
#define TFR(r) { x0 += x1; x1 = (x1 << (r)) | (x1 >> (32 - (r))); x1 ^= x0; }
  TFR(13) TFR(15) TFR(26) TFR(6)
  x0 += k1;  x1 += ks2 + 1u;
  TFR(17) TFR(29) TFR(16) TFR(24)
  x0 += ks2; x1 += k0 + 2u;
  TFR(13) TFR(15) TFR(26) TFR(6)
  x0 += k0;  x1 += k1 + 3u;
  TFR(17) TFR(29) TFR(16) TFR(24)
  x0 += k1;  x1 += ks2 + 4u;
  TFR(13) TFR(15) TFR(26) TFR(6)
  x0 += ks2; x1 += k0 + 5u;
#undef TFR
  o0 = x0; o1 = x1;
}

// NOTE: parameter names must not collide with float4 member names (.x/.y/.z/.w)
#define ACC4(acc, Wv, Vv) \
  acc = fma((double)(Wv).x, (double)(Vv).x, acc); \
  acc = fma((double)(Wv).y, (double)(Vv).y, acc); \
  acc = fma((double)(Wv).z, (double)(Vv).z, acc); \
  acc = fma((double)(Wv).w, (double)(Vv).w, acc);

// Pack weights: LSTM [512,128] -> P[(k>>2)*2048 + r*4 + (k&3)]
//               attn [128,128] -> P[(k>>2)*512  + o*4 + (k&3)]
// so lane u loads float4 {k..k+3} of row u at a lane-consecutive address.
__global__ void prep_kernel(const float* __restrict__ eWih, const float* __restrict__ eWhh,
                            const float* __restrict__ dWih, const float* __restrict__ dWhh,
                            const float* __restrict__ gWq,  const float* __restrict__ gWref,
                            const float* __restrict__ pWq,  const float* __restrict__ pWref,
                            float* __restrict__ ws) {
  int id = blockIdx.x * blockDim.x + threadIdx.x;
  if (id < 262144) {
    int m = id >> 16, e = id & 65535;
    const float* src = (m == 0) ? eWih : (m == 1) ? eWhh : (m == 2) ? dWih : dWhh;
    int r = e >> 7, k = e & 127;
    ws[m * 65536 + (k >> 2) * 2048 + r * 4 + (k & 3)] = src[e];
  } else if (id < 327680) {
    int a = id - 262144;
    int m = a >> 14, e = a & 16383;
    const float* src = (m == 0) ? gWq : (m == 1) ? gWref : (m == 2) ? pWq : pWref;
    int o = e >> 7, k = e & 127;
    ws[262144 + m * 16384 + (k >> 2) * 512 + o * 4 + (k & 3)] = src[e];
  }
}

static __device__ __forceinline__ void lstm_step(
    int u, const float4* __restrict__ PIH, const float4* __restrict__ PHH,
    const float* __restrict__ bih, const float* __restrict__ bhh,
    const float4* __restrict__ xr, const float4* __restrict__ hr,
    float &c, float &hout)
{
  double di = 0, df = 0, dg = 0, dd = 0;
  double ei = 0, ef = 0, eg = 0, eo = 0;
#pragma unroll 4
  for (int k4 = 0; k4 < 32; k4++) {
    float4 xv = xr[k4];
    float4 hv = hr[k4];
    float4 w0 = PIH[k4 * 512 + u];
    float4 w1 = PIH[k4 * 512 + u + 128];
    float4 w2 = PIH[k4 * 512 + u + 256];
    float4 w3 = PIH[k4 * 512 + u + 384];
    ACC4(di, w0, xv) ACC4(df, w1, xv) ACC4(dg, w2, xv) ACC4(dd, w3, xv)
    float4 v0 = PHH[k4 * 512 + u];
    float4 v1 = PHH[k4 * 512 + u + 128];
    float4 v2 = PHH[k4 * 512 + u + 256];
    float4 v3 = PHH[k4 * 512 + u + 384];
    ACC4(ei, v0, hv) ACC4(ef, v1, hv) ACC4(eg, v2, hv) ACC4(eo, v3, hv)
  }
  // ((x@Wih^T + bih) + h@Whh^T) + bhh  -- XLA add tree order
  float gi = f_add(f_add(f_add((float)di, bih[u      ]), (float)ei), bhh[u      ]);
  float gf = f_add(f_add(f_add((float)df, bih[u + 128]), (float)ef), bhh[u + 128]);
  float gg = f_add(f_add(f_add((float)dg, bih[u + 256]), (float)eg), bhh[u + 256]);
  float go = f_add(f_add(f_add((float)dd, bih[u + 384]), (float)eo), bhh[u + 384]);
  float I = sigmoid_xla(gi);
  float F = sigmoid_xla(gf);
  float G = tanh_xla(gg);
  float O = sigmoid_xla(go);
  c = f_add(f_mul(F, c), f_mul(I, G));
  hout = f_mul(O, tanh_xla(c));
}

__global__ void __launch_bounds__(128)
pnet_kernel(const float* __restrict__ bi, const float* __restrict__ emb,
            const float* __restrict__ ebih, const float* __restrict__ ebhh,
            const float* __restrict__ dbih, const float* __restrict__ dbhh,
            const float* __restrict__ gbq, const float* __restrict__ gbref, const float* __restrict__ gV,
            const float* __restrict__ pbq, const float* __restrict__ pbref, const float* __restrict__ pV,
            const float* __restrict__ dstart,
            float* __restrict__ ws, float* __restrict__ out)
{
  __shared__ __align__(16) float sRG[50 * RSTR];   // 26400 B
  __shared__ __align__(16) float sRP[50 * RSTR];   // 26400 B
  __shared__ __align__(16) float sh_h[128];
  __shared__ __align__(16) float sh_x[128];
  __shared__ __align__(16) float sh_q[128];
  __shared__ __align__(16) float sh_q2[128];
  __shared__ float sh_att[64];
  __shared__ float sh_w[64];
  __shared__ unsigned long long sh_msk;
  __shared__ int sh_idx;

  const int i  = threadIdx.x;        // 0..127, hidden unit owned by thread
  const int gb = blockIdx.x;         // batch element

  const float4* PIH_E = (const float4*)(ws + OFF_PIH_E);
  const float4* PHH_E = (const float4*)(ws + OFF_PHH_E);
  const float4* PIH_D = (const float4*)(ws + OFF_PIH_D);
  const float4* PHH_D = (const float4*)(ws + OFF_PHH_D);
  const float4* PQG = (const float4*)(ws + OFF_PQG);
  const float4* PRG = (const float4*)(ws + OFF_PRG);
  const float4* PQP = (const float4*)(ws + OFF_PQP);
  const float4* PRP = (const float4*)(ws + OFF_PRP);

  const float NEG_INF = -__builtin_inff();

  sh_h[i] = 0.0f;
  if (i == 0) sh_msk = 0ull;
  float c_st = 0.0f;
  __syncthreads();

  // ---------------- encoder + fused ref projections ----------------
  for (int t = 0; t < 50; t++) {
    {
      float x0 = bi[gb * 100 + t];
      float x1 = bi[gb * 100 + 50 + t];
      sh_x[i] = __fmaf_rn(x1, emb[128 + i], f_mul(x0, emb[i]));
    }
    __syncthreads();
    float hn;
    lstm_step(i, PIH_E, PHH_E, ebih, ebhh,
              (const float4*)sh_x, (const float4*)sh_h, c_st, hn);
    __syncthreads();
    sh_h[i] = hn;
    __syncthreads();
    // rg[t][i] = gWref_row_i . h + gbref[i]; rp likewise (Conv1d k=1 fused)
    {
      double ag = 0, ap = 0;
      const float4* hr = (const float4*)sh_h;
#pragma unroll 4
      for (int k4 = 0; k4 < 32; k4++) {
        float4 xv = hr[k4];
        float4 wg = PRG[k4 * 128 + i];
        float4 wp = PRP[k4 * 128 + i];
        ACC4(ag, wg, xv) ACC4(ap, wp, xv)
      }
      sRG[t * RSTR + i] = f_add((float)ag, gbref[i]);
      sRP[t * RSTR + i] = f_add((float)ap, pbref[i]);
    }
    // next sh_h write is beyond two barriers; sRG/sRP only read in decoder
  }
  sh_x[i] = dstart[i];   // decoder initial input
  __syncthreads();

  // ---------------- decoder ----------------
  for (int t = 0; t < 50; t++) {
    // partitionable threefry:
    //   fk = fold_in(key(42), t) = tf((0,42), (0,t))
    //   k1 = split(fk, 2)[0]     = tf(fk, (0,0))   [foldlike: both words]
    uint32_t f0, f1, k1a, k1b;
    tf2x32(0u, 42u, 0u, (uint32_t)t, f0, f1);
    tf2x32(f0, f1, 0u, 0u, k1a, k1b);

    float hn;
    lstm_step(i, PIH_D, PHH_D, dbih, dbhh,
              (const float4*)sh_x, (const float4*)sh_h, c_st, hn);
    __syncthreads();                                  // B1
    sh_h[i] = hn;
    __syncthreads();                                  // B2

    // glimpse query: qg = Wq_g @ h + bq_g
    {
      double a = 0;
      const float4* hr = (const float4*)sh_h;
#pragma unroll 4
      for (int k4 = 0; k4 < 32; k4++) {
        float4 wv = PQG[k4 * 128 + i];
        float4 xv = hr[k4];
        ACC4(a, wv, xv)
      }
      sh_q[i] = f_add((float)a, gbq[i]);
    }
    __syncthreads();                                  // B3

    // glimpse logits: lg[s] = sum_h V[h]*tanh(qg[h]+ref_g[s][h]) ; mask
    {
      double acc = 0.0;
      const int s = i >> 1, hf = (i & 1) * 64;
      if (i < 100) {
        const float4* rr = (const float4*)(sRG + s * RSTR + hf);
        const float4* qq = (const float4*)(sh_q + hf);
        const float4* vvp = (const float4*)(gV + hf);
#pragma unroll 2
        for (int k4 = 0; k4 < 16; k4++) {
          float4 rv = rr[k4];
          float4 qv = qq[k4];
          float4 gvv = vvp[k4];
          acc = fma((double)gvv.x, (double)tanh_xla(f_add(qv.x, rv.x)), acc);
          acc = fma((double)gvv.y, (double)tanh_xla(f_add(qv.y, rv.y)), acc);
          acc = fma((double)gvv.z, (double)tanh_xla(f_add(qv.z, rv.z)), acc);
          acc = fma((double)gvv.w, (double)tanh_xla(f_add(qv.w, rv.w)), acc);
        }
      }
      double tot = acc + __shfl_xor(acc, 1);
      if (i < 100 && (i & 1) == 0) {
        float lg = (float)tot;
        sh_att[s] = ((sh_msk >> s) & 1ull) ? NEG_INF : lg;
      }
      if (i >= 100 && i < 114) sh_att[i - 50] = NEG_INF;   // pad 50..63
    }
    __syncthreads();                                  // B4

    // glimpse softmax (wave 0; sum via register shuffles, XLA s-order)
    if (i < 64) {
      float v = sh_att[i];
      float m = v;
      for (int off = 32; off > 0; off >>= 1) m = fmaxf(m, __shfl_xor(m, off));
      float e = (i < 50) ? expf(f_sub(v, m)) : 0.0f;
      float ss = 0.0f;
      for (int s2 = 0; s2 < 50; s2++) ss = f_add(ss, __shfl(e, s2));
      float wv = __fdiv_rn(e, ss);
      sh_w[i] = (i < 50) ? wv : 0.0f;
    }
    __syncthreads();                                  // B5

    // q2 = sum_s w[s] * ref_g[s][:]
    {
      double a = 0;
      for (int s2 = 0; s2 < 50; s2++) {
        float wv = sh_w[s2];
        float rv = sRG[s2 * RSTR + i];
        a = fma((double)rv, (double)wv, a);
      }
      sh_q2[i] = (float)a;
    }
    __syncthreads();                                  // B6

    // pointer query: qp = Wq_p @ q2 + bq_p
    {
      double a = 0;
      const float4* qr = (const float4*)sh_q2;
#pragma unroll 4
      for (int k4 = 0; k4 < 32; k4++) {
        float4 wv = PQP[k4 * 128 + i];
        float4 xv = qr[k4];
        ACC4(a, wv, xv)
      }
      sh_q[i] = f_add((float)a, pbq[i]);
    }
    __syncthreads();                                  // B7

    // pointer logits + 10*tanh + mask
    {
      double acc = 0.0;
      const int s = i >> 1, hf = (i & 1) * 64;
      if (i < 100) {
        const float4* rr = (const float4*)(sRP + s * RSTR + hf);
        const float4* qq = (const float4*)(sh_q + hf);
        const float4* vvp = (const float4*)(pV + hf);
#pragma unroll 2
        for (int k4 = 0; k4 < 16; k4++) {
          float4 rv = rr[k4];
          float4 qv = qq[k4];
          float4 pvv = vvp[k4];
          acc = fma((double)pvv.x, (double)tanh_xla(f_add(qv.x, rv.x)), acc);
          acc = fma((double)pvv.y, (double)tanh_xla(f_add(qv.y, rv.y)), acc);
          acc = fma((double)pvv.z, (double)tanh_xla(f_add(qv.z, rv.z)), acc);
          acc = fma((double)pvv.w, (double)tanh_xla(f_add(qv.w, rv.w)), acc);
        }
      }
      double tot = acc + __shfl_xor(acc, 1);
      if (i < 100 && (i & 1) == 0) {
        float lp = (float)tot;
        lp = f_mul(10.0f, tanh_xla(lp));
        sh_att[s] = ((sh_msk >> s) & 1ull) ? NEG_INF : lp;
      }
      if (i >= 100 && i < 114) sh_att[i - 50] = NEG_INF;
    }
    __syncthreads();                                  // B8

    // probs output + gumbel sampling (wave 0; shuffle-based sum)
    if (i < 64) {
      float v = sh_att[i];
      float m = v;
      for (int off = 32; off > 0; off >>= 1) m = fmaxf(m, __shfl_xor(m, off));
      float e = (i < 50) ? expf(f_sub(v, m)) : 0.0f;
      float ss = 0.0f;
      for (int s2 = 0; s2 < 50; s2++) ss = f_add(ss, __shfl(e, s2));
      if (i < 50) out[t * 25600 + gb * 50 + i] = __fdiv_rn(e, ss);

      float val = NEG_INF;
      int ii = i;
      if (i < 50) {
        int j = gb * 50 + i;               // flat index into (B,S) gumbel draw
        // partitionable random_bits(32): bits[j] = o0 ^ o1 of tf(k1, (0, j))
        uint32_t b0, b1;
        tf2x32(k1a, k1b, 0u, (uint32_t)j, b0, b1);
        uint32_t bits = b0 ^ b1;
        float fl = __uint_as_float((bits >> 9) | 0x3f800000u) - 1.0f;  // [0,1)
        float u = f_add(fl, TINYF);         // floats*(1-tiny==1.0f) + tiny
        u = fmaxf(TINYF, u);
        float gum = -logf(-logf(u));
        val = f_add(v, gum);                // -inf stays -inf for masked
      }
      // argmax, first-index tiebreak (jnp.argmax semantics)
      for (int off = 32; off > 0; off >>= 1) {
        float ov = __shfl_down(val, off);
        int   oi = __shfl_down(ii, off);
        if (ov > val || (ov == val && oi < ii)) { val = ov; ii = oi; }
      }
      if (i == 0) {
        sh_idx = ii;
        sh_msk |= (1ull << ii);             // masks step t+1 onward
        out[1280000 + t * 512 + gb] = (float)ii;
      }
    }
    __syncthreads();                                  // B9

    // next decoder input: embedded[b, idx]
    {
      int idx = sh_idx;
      float x0 = bi[gb * 100 + idx];
      float x1 = bi[gb * 100 + 50 + idx];
      sh_x[i] = __fmaf_rn(x1, emb[128 + i], f_mul(x0, emb[i]));
    }
    __syncthreads();                                  // B10
  }
}

extern "C" void kernel_launch(void* const* d_in, const int* in_sizes, int n_in,
                              void* d_out, int out_size, void* d_ws, size_t ws_size,
                              hipStream_t stream) {
  const float* bi     = (const float*)d_in[0];
  const float* emb    = (const float*)d_in[1];
  const float* eWih   = (const float*)d_in[2];
  const float* eWhh   = (const float*)d_in[3];
  const float* ebih   = (const float*)d_in[4];
  const float* ebhh   = (const float*)d_in[5];
  const float* dWih   = (const float*)d_in[6];
  const float* dWhh   = (const float*)d_in[7];
  const float* dbih   = (const float*)d_in[8];
  const float* dbhh   = (const float*)d_in[9];
  const float* gWq    = (const float*)d_in[10];
  const float* gbq    = (const float*)d_in[11];
  const float* gWref  = (const float*)d_in[12];
  const float* gbref  = (const float*)d_in[13];
  const float* gV     = (const float*)d_in[14];
  const float* pWq    = (const float*)d_in[15];
  const float* pbq    = (const float*)d_in[16];
  const float* pWref  = (const float*)d_in[17];
  const float* pbref  = (const float*)d_in[18];
  const float* pV     = (const float*)d_in[19];
  const float* dstart = (const float*)d_in[20];
  float* ws  = (float*)d_ws;
  float* out = (float*)d_out;

  hipLaunchKernelGGL(prep_kernel, dim3(1280), dim3(256), 0, stream,
                     eWih, eWhh, dWih, dWhh, gWq, gWref, pWq, pWref, ws);
  hipLaunchKernelGGL(pnet_kernel, dim3(512), dim3(128), 0, stream,
                     bi, emb, ebih, ebhh, dbih, dbhh,
                     gbq, gbref, gV, pbq, pbref, pV, dstart, ws, out);
}

// Round 6
// 1605.478 us; speedup vs baseline: 1.2586x; 1.2586x over previous
//
#include <hip/hip_runtime.h>
#include <stdint.h>

// PointerNet fused forward. B=512, S=50, E=H=128.
// 512 blocks x 256 threads (4 waves), 1 batch element per block.
// k-SPLIT LAYOUT: wave w owns units 32w..32w+31; lane l handles
// (unit = 32w + (l&31), half = l>>5); the two k-halves of every dot product
// are combined with one f64 shfl_xor(32) (same wave). Gate math is computed
// redundantly by both halves (identical bits). This halves the per-thread
// FMA chain AND doubles waves/SIMD (1 -> 2) vs round 5.
// RG/RP live in LDS (stride 132), fused with the encoder. ws holds only
// packed weights (1.31 MB), rewritten with identical values every call.
// All cross-lane communication is LDS write -> __syncthreads -> read, or
// register shuffles (round-5 hardening).
// Dot products accumulate in f64 (single rounding to f32); elementwise math
// replicates XLA CPU bit patterns (tanh rational poly, logistic-as-tanh,
// sequential softmax sum). Sampling replicates jax.random.categorical with
// THREEFRY PARTITIONABLE mode (JAX >= 0.5 default):
//   fold_in: key' = tf2x32(key, (0, t))
//   split (foldlike): k1 = tf2x32(key', (0, 0))   [both output words]
//   random_bits(32): bits[j] = o0 ^ o1 of tf2x32(k1, (0, j))
// uniform->gumbel exactly as jax._src.random; argmax with first-index ties.

#define OFF_PIH_E 0
#define OFF_PHH_E 65536
#define OFF_PIH_D 131072
#define OFF_PHH_D 196608
#define OFF_PQG   262144
#define OFF_PRG   278528
#define OFF_PQP   294912
#define OFF_PRP   311296
// ws total: 327680 floats = 1.31 MB

#define RSTR 132   // LDS row stride for RG/RP (16B-aligned)

#define TINYF 1.1754943508222875e-38f

static __device__ __forceinline__ float f_add(float a, float b){ return __fadd_rn(a,b); }
static __device__ __forceinline__ float f_mul(float a, float b){ return __fmul_rn(a,b); }
static __device__ __forceinline__ float f_sub(float a, float b){ return __fsub_rn(a,b); }

static __device__ __forceinline__ double shfl_xor_d(double v, int mask) {
  long long x = __double_as_longlong(v);
  int lo = (int)(x & 0xffffffffll);
  int hi = (int)(x >> 32);
  lo = __shfl_xor(lo, mask);
  hi = __shfl_xor(hi, mask);
  return __longlong_as_double(((long long)hi << 32) | (unsigned long long)(unsigned int)lo);
}

// XLA CPU tanh: elemental_ir_emitter rational approximation, unfused mul/add.
static __device__ __forceinline__ float tanh_xla(float x) {
  float xc = fminf(fmaxf(x, -7.90531110763549805f), 7.90531110763549805f);
  float x2 = f_mul(xc, xc);
  float p;
  p = -2.76076847742355e-16f;
  p = f_add(f_mul(p, x2),  2.00018790482477e-13f);
  p = f_add(f_mul(p, x2), -8.60467152213735e-11f);
  p = f_add(f_mul(p, x2),  5.12229709037114e-08f);
  p = f_add(f_mul(p, x2),  1.48572235717979e-05f);
  p = f_add(f_mul(p, x2),  6.37261928875436e-04f);
  p = f_add(f_mul(p, x2),  4.89352455891786e-03f);
  p = f_mul(xc, p);
  float q;
  q = 1.19825839466702e-06f;
  q = f_add(f_mul(q, x2), 1.18534705686654e-04f);
  q = f_add(f_mul(q, x2), 2.26843463243900e-03f);
  q = f_add(f_mul(q, x2), 4.89352518554385e-03f);
  float r = __fdiv_rn(p, q);
  return (fabsf(x) < 0.0004f) ? x : r;
}

// XLA logistic expansion: 0.5 + 0.5*tanh(0.5*x)
static __device__ __forceinline__ float sigmoid_xla(float x) {
  return f_add(0.5f, f_mul(0.5f, tanh_xla(f_mul(0.5f, x))));
}

// Threefry-2x32, 20 rounds (JAX key schedule)
static __device__ __forceinline__ void tf2x32(uint32_t k0, uint32_t k1,
                                              uint32_t x0, uint32_t x1,
                                              uint32_t &o0, uint32_t &o1) {
  uint32_t ks2 = k0 ^ k1 ^ 0x1BD11BDAu;
  x0 += k0; x1 += k1;
#define TFR(r) { x0 += x1; x1 = (x1 << (r)) | (x1 >> (32 - (r))); x1 ^= x0; }
  TFR(13) TFR(15) TFR(26) TFR(6)
  x0 += k1;  x1 += ks2 + 1u;
  TFR(17) TFR(29) TFR(16) TFR(24)
  x0 += ks2; x1 += k0 + 2u;
  TFR(13) TFR(15) TFR(26) TFR(6)
  x0 += k0;  x1 += k1 + 3u;
  TFR(17) TFR(29) TFR(16) TFR(24)
  x0 += k1;  x1 += ks2 + 4u;
  TFR(13) TFR(15) TFR(26) TFR(6)
  x0 += ks2; x1 += k0 + 5u;
#undef TFR
  o0 = x0; o1 = x1;
}

// NOTE: parameter names must not collide with float4 member names (.x/.y/.z/.w)
#define ACC4(acc, Wv, Vv) \
  acc = fma((double)(Wv).x, (double)(Vv).x, acc); \
  acc = fma((double)(Wv).y, (double)(Vv).y, acc); \
  acc = fma((double)(Wv).z, (double)(Vv).z, acc); \
  acc = fma((double)(Wv).w, (double)(Vv).w, acc);

// Pack weights: LSTM [512,128] -> P[(k>>2)*2048 + r*4 + (k&3)]
//               attn [128,128] -> P[(k>>2)*512  + o*4 + (k&3)]
// so a lane loads float4 {k..k+3} of row r at a lane-consecutive address.
__global__ void prep_kernel(const float* __restrict__ eWih, const float* __restrict__ eWhh,
                            const float* __restrict__ dWih, const float* __restrict__ dWhh,
                            const float* __restrict__ gWq,  const float* __restrict__ gWref,
                            const float* __restrict__ pWq,  const float* __restrict__ pWref,
                            float* __restrict__ ws) {
  int id = blockIdx.x * blockDim.x + threadIdx.x;
  if (id < 262144) {
    int m = id >> 16, e = id & 65535;
    const float* src = (m == 0) ? eWih : (m == 1) ? eWhh : (m == 2) ? dWih : dWhh;
    int r = e >> 7, k = e & 127;
    ws[m * 65536 + (k >> 2) * 2048 + r * 4 + (k & 3)] = src[e];
  } else if (id < 327680) {
    int a = id - 262144;
    int m = a >> 14, e = a & 16383;
    const float* src = (m == 0) ? gWq : (m == 1) ? gWref : (m == 2) ? pWq : pWref;
    int o = e >> 7, k = e & 127;
    ws[262144 + m * 16384 + (k >> 2) * 512 + o * 4 + (k & 3)] = src[e];
  }
}

// Half-k LSTM step: thread covers k4 in [kb, kb+16); partials combined via
// shfl_xor(32); gate math redundant on both halves (identical bits).
static __device__ __forceinline__ void lstm_step2(
    int u, int kb, const float4* __restrict__ PIH, const float4* __restrict__ PHH,
    const float* __restrict__ bih, const float* __restrict__ bhh,
    const float4* __restrict__ xr, const float4* __restrict__ hr,
    float &c, float &hout)
{
  double di = 0, df = 0, dg = 0, dd = 0;
  double ei = 0, ef = 0, eg = 0, eo = 0;
#pragma unroll 4
  for (int kk = 0; kk < 16; kk++) {
    int k4 = kb + kk;
    float4 xv = xr[k4];
    float4 hv = hr[k4];
    float4 w0 = PIH[k4 * 512 + u];
    float4 w1 = PIH[k4 * 512 + u + 128];
    float4 w2 = PIH[k4 * 512 + u + 256];
    float4 w3 = PIH[k4 * 512 + u + 384];
    ACC4(di, w0, xv) ACC4(df, w1, xv) ACC4(dg, w2, xv) ACC4(dd, w3, xv)
    float4 v0 = PHH[k4 * 512 + u];
    float4 v1 = PHH[k4 * 512 + u + 128];
    float4 v2 = PHH[k4 * 512 + u + 256];
    float4 v3 = PHH[k4 * 512 + u + 384];
    ACC4(ei, v0, hv) ACC4(ef, v1, hv) ACC4(eg, v2, hv) ACC4(eo, v3, hv)
  }
  di += shfl_xor_d(di, 32); df += shfl_xor_d(df, 32);
  dg += shfl_xor_d(dg, 32); dd += shfl_xor_d(dd, 32);
  ei += shfl_xor_d(ei, 32); ef += shfl_xor_d(ef, 32);
  eg += shfl_xor_d(eg, 32); eo += shfl_xor_d(eo, 32);
  // ((x@Wih^T + bih) + h@Whh^T) + bhh  -- XLA add tree order
  float gi = f_add(f_add(f_add((float)di, bih[u      ]), (float)ei), bhh[u      ]);
  float gf = f_add(f_add(f_add((float)df, bih[u + 128]), (float)ef), bhh[u + 128]);
  float gg = f_add(f_add(f_add((float)dg, bih[u + 256]), (float)eg), bhh[u + 256]);
  float go = f_add(f_add(f_add((float)dd, bih[u + 384]), (float)eo), bhh[u + 384]);
  float I = sigmoid_xla(gi);
  float F = sigmoid_xla(gf);
  float G = tanh_xla(gg);
  float O = sigmoid_xla(go);
  c = f_add(f_mul(F, c), f_mul(I, G));
  hout = f_mul(O, tanh_xla(c));
}

__global__ void __launch_bounds__(256)
pnet_kernel(const float* __restrict__ bi, const float* __restrict__ emb,
            const float* __restrict__ ebih, const float* __restrict__ ebhh,
            const float* __restrict__ dbih, const float* __restrict__ dbhh,
            const float* __restrict__ gbq, const float* __restrict__ gbref, const float* __restrict__ gV,
            const float* __restrict__ pbq, const float* __restrict__ pbref, const float* __restrict__ pV,
            const float* __restrict__ dstart,
            float* __restrict__ ws, float* __restrict__ out)
{
  __shared__ __align__(16) float sRG[50 * RSTR];   // 26400 B
  __shared__ __align__(16) float sRP[50 * RSTR];   // 26400 B
  __shared__ __align__(16) float sh_h[128];
  __shared__ __align__(16) float sh_x[128];
  __shared__ __align__(16) float sh_q[128];
  __shared__ __align__(16) float sh_q2[128];
  __shared__ float sh_att[64];
  __shared__ float sh_w[64];
  __shared__ unsigned long long sh_msk;
  __shared__ int sh_idx;

  const int tid  = threadIdx.x;            // 0..255
  const int l    = tid & 63;               // lane in wave
  const int u    = (tid >> 6) * 32 + (l & 31);   // unit 0..127
  const int half = l >> 5;                 // k-half 0/1 (same wave as partner)
  const int kb   = half * 16;              // base k4
  const bool h0  = (half == 0);
  const int gb   = blockIdx.x;             // batch element

  const float4* PIH_E = (const float4*)(ws + OFF_PIH_E);
  const float4* PHH_E = (const float4*)(ws + OFF_PHH_E);
  const float4* PIH_D = (const float4*)(ws + OFF_PIH_D);
  const float4* PHH_D = (const float4*)(ws + OFF_PHH_D);
  const float4* PQG = (const float4*)(ws + OFF_PQG);
  const float4* PRG = (const float4*)(ws + OFF_PRG);
  const float4* PQP = (const float4*)(ws + OFF_PQP);
  const float4* PRP = (const float4*)(ws + OFF_PRP);

  const float NEG_INF = -__builtin_inff();

  if (tid < 128) sh_h[tid] = 0.0f;
  if (tid == 0) sh_msk = 0ull;
  float c_st = 0.0f;
  __syncthreads();

  // ---------------- encoder + fused ref projections ----------------
  for (int t = 0; t < 50; t++) {
    if (h0) {
      float x0 = bi[gb * 100 + t];
      float x1 = bi[gb * 100 + 50 + t];
      sh_x[u] = __fmaf_rn(x1, emb[128 + u], f_mul(x0, emb[u]));
    }
    __syncthreads();
    float hn;
    lstm_step2(u, kb, PIH_E, PHH_E, ebih, ebhh,
               (const float4*)sh_x, (const float4*)sh_h, c_st, hn);
    __syncthreads();
    if (h0) sh_h[u] = hn;
    __syncthreads();
    // rg[t][u] = gWref_row_u . h + gbref[u]; rp likewise (Conv1d k=1 fused)
    {
      double ag = 0, ap = 0;
      const float4* hr = (const float4*)sh_h;
#pragma unroll 4
      for (int kk = 0; kk < 16; kk++) {
        int k4 = kb + kk;
        float4 xv = hr[k4];
        float4 wg = PRG[k4 * 128 + u];
        float4 wp = PRP[k4 * 128 + u];
        ACC4(ag, wg, xv) ACC4(ap, wp, xv)
      }
      ag += shfl_xor_d(ag, 32);
      ap += shfl_xor_d(ap, 32);
      if (h0) {
        sRG[t * RSTR + u] = f_add((float)ag, gbref[u]);
        sRP[t * RSTR + u] = f_add((float)ap, pbref[u]);
      }
    }
    // loop-top sh_x write is safe: its readers finished before barrier 2
  }
  if (h0) sh_x[u] = dstart[u];   // decoder initial input
  __syncthreads();

  // ---------------- decoder ----------------
  for (int t = 0; t < 50; t++) {
    // partitionable threefry:
    //   fk = fold_in(key(42), t) = tf((0,42), (0,t))
    //   k1 = split(fk, 2)[0]     = tf(fk, (0,0))   [foldlike: both words]
    uint32_t f0, f1, k1a, k1b;
    tf2x32(0u, 42u, 0u, (uint32_t)t, f0, f1);
    tf2x32(f0, f1, 0u, 0u, k1a, k1b);

    float hn;
    lstm_step2(u, kb, PIH_D, PHH_D, dbih, dbhh,
               (const float4*)sh_x, (const float4*)sh_h, c_st, hn);
    __syncthreads();                                  // B1
    if (h0) sh_h[u] = hn;
    __syncthreads();                                  // B2

    // glimpse query: qg = Wq_g @ h + bq_g
    {
      double a = 0;
      const float4* hr = (const float4*)sh_h;
#pragma unroll 4
      for (int kk = 0; kk < 16; kk++) {
        int k4 = kb + kk;
        float4 wv = PQG[k4 * 128 + u];
        float4 xv = hr[k4];
        ACC4(a, wv, xv)
      }
      double tot = a + shfl_xor_d(a, 32);
      if (h0) sh_q[u] = f_add((float)tot, gbq[u]);
    }
    __syncthreads();                                  // B3

    // glimpse logits: lg[s] = sum_h V[h]*tanh(qg[h]+ref_g[s][h]); 4 lanes/row
    {
      double acc = 0.0;
      const int s = tid >> 2, hf = (tid & 3) * 32;
      if (tid < 200) {
        const float4* rr = (const float4*)(sRG + s * RSTR + hf);
        const float4* qq = (const float4*)(sh_q + hf);
        const float4* vvp = (const float4*)(gV + hf);
#pragma unroll 2
        for (int k4 = 0; k4 < 8; k4++) {
          float4 rv = rr[k4];
          float4 qv = qq[k4];
          float4 gvv = vvp[k4];
          acc = fma((double)gvv.x, (double)tanh_xla(f_add(qv.x, rv.x)), acc);
          acc = fma((double)gvv.y, (double)tanh_xla(f_add(qv.y, rv.y)), acc);
          acc = fma((double)gvv.z, (double)tanh_xla(f_add(qv.z, rv.z)), acc);
          acc = fma((double)gvv.w, (double)tanh_xla(f_add(qv.w, rv.w)), acc);
        }
      }
      double tot = acc + shfl_xor_d(acc, 1);
      tot = tot + shfl_xor_d(tot, 2);
      if (tid < 200 && (tid & 3) == 0) {
        float lg = (float)tot;
        sh_att[s] = ((sh_msk >> s) & 1ull) ? NEG_INF : lg;
      }
      if (tid >= 200 && tid < 214) sh_att[tid - 150] = NEG_INF;   // pad 50..63
    }
    __syncthreads();                                  // B4

    // glimpse softmax (wave 0; sum via register shuffles, XLA s-order)
    if (tid < 64) {
      float v = sh_att[tid];
      float m = v;
      for (int off = 32; off > 0; off >>= 1) m = fmaxf(m, __shfl_xor(m, off));
      float e = (tid < 50) ? expf(f_sub(v, m)) : 0.0f;
      float ss = 0.0f;
      for (int s2 = 0; s2 < 50; s2++) ss = f_add(ss, __shfl(e, s2));
      float wv = __fdiv_rn(e, ss);
      sh_w[tid] = (tid < 50) ? wv : 0.0f;
    }
    __syncthreads();                                  // B5

    // q2 = sum_s w[s] * ref_g[s][:]  (halves: s 0..24 / 25..49)
    {
      double a = 0;
      const int s0 = half * 25;
      for (int s2 = s0; s2 < s0 + 25; s2++) {
        float wv = sh_w[s2];
        float rv = sRG[s2 * RSTR + u];
        a = fma((double)rv, (double)wv, a);
      }
      double tot = a + shfl_xor_d(a, 32);
      if (h0) sh_q2[u] = (float)tot;
    }
    __syncthreads();                                  // B6

    // pointer query: qp = Wq_p @ q2 + bq_p
    {
      double a = 0;
      const float4* qr = (const float4*)sh_q2;
#pragma unroll 4
      for (int kk = 0; kk < 16; kk++) {
        int k4 = kb + kk;
        float4 wv = PQP[k4 * 128 + u];
        float4 xv = qr[k4];
        ACC4(a, wv, xv)
      }
      double tot = a + shfl_xor_d(a, 32);
      if (h0) sh_q[u] = f_add((float)tot, pbq[u]);
    }
    __syncthreads();                                  // B7

    // pointer logits + 10*tanh + mask; 4 lanes/row
    {
      double acc = 0.0;
      const int s = tid >> 2, hf = (tid & 3) * 32;
      if (tid < 200) {
        const float4* rr = (const float4*)(sRP + s * RSTR + hf);
        const float4* qq = (const float4*)(sh_q + hf);
        const float4* vvp = (const float4*)(pV + hf);
#pragma unroll 2
        for (int k4 = 0; k4 < 8; k4++) {
          float4 rv = rr[k4];
          float4 qv = qq[k4];
          float4 pvv = vvp[k4];
          acc = fma((double)pvv.x, (double)tanh_xla(f_add(qv.x, rv.x)), acc);
          acc = fma((double)pvv.y, (double)tanh_xla(f_add(qv.y, rv.y)), acc);
          acc = fma((double)pvv.z, (double)tanh_xla(f_add(qv.z, rv.z)), acc);
          acc = fma((double)pvv.w, (double)tanh_xla(f_add(qv.w, rv.w)), acc);
        }
      }
      double tot = acc + shfl_xor_d(acc, 1);
      tot = tot + shfl_xor_d(tot, 2);
      if (tid < 200 && (tid & 3) == 0) {
        float lp = (float)tot;
        lp = f_mul(10.0f, tanh_xla(lp));
        sh_att[s] = ((sh_msk >> s) & 1ull) ? NEG_INF : lp;
      }
      if (tid >= 200 && tid < 214) sh_att[tid - 150] = NEG_INF;
    }
    __syncthreads();                                  // B8

    // probs output + gumbel sampling (wave 0; shuffle-based sum)
    if (tid < 64) {
      float v = sh_att[tid];
      float m = v;
      for (int off = 32; off > 0; off >>= 1) m = fmaxf(m, __shfl_xor(m, off));
      float e = (tid < 50) ? expf(f_sub(v, m)) : 0.0f;
      float ss = 0.0f;
      for (int s2 = 0; s2 < 50; s2++) ss = f_add(ss, __shfl(e, s2));
      if (tid < 50) out[t * 25600 + gb * 50 + tid] = __fdiv_rn(e, ss);

      float val = NEG_INF;
      int ii = tid;
      if (tid < 50) {
        int j = gb * 50 + tid;             // flat index into (B,S) gumbel draw
        // partitionable random_bits(32): bits[j] = o0 ^ o1 of tf(k1, (0, j))
        uint32_t b0, b1;
        tf2x32(k1a, k1b, 0u, (uint32_t)j, b0, b1);
        uint32_t bits = b0 ^ b1;
        float fl = __uint_as_float((bits >> 9) | 0x3f800000u) - 1.0f;  // [0,1)
        float uu = f_add(fl, TINYF);
        uu = fmaxf(TINYF, uu);
        float gum = -logf(-logf(uu));
        val = f_add(v, gum);               // -inf stays -inf for masked
      }
      // argmax, first-index tiebreak (jnp.argmax semantics)
      for (int off = 32; off > 0; off >>= 1) {
        float ov = __shfl_down(val, off);
        int   oi = __shfl_down(ii, off);
        if (ov > val || (ov == val && oi < ii)) { val = ov; ii = oi; }
      }
      if (tid == 0) {
        sh_idx = ii;
        sh_msk |= (1ull << ii);            // masks step t+1 onward
        out[1280000 + t * 512 + gb] = (float)ii;
      }
    }
    __syncthreads();                                  // B9

    // next decoder input: embedded[b, idx]
    if (h0) {
      int idx = sh_idx;
      float x0 = bi[gb * 100 + idx];
      float x1 = bi[gb * 100 + 50 + idx];
      sh_x[u] = __fmaf_rn(x1, emb[128 + u], f_mul(x0, emb[u]));
    }
    __syncthreads();                                  // B10
  }
}

extern "C" void kernel_launch(void* const* d_in, const int* in_sizes, int n_in,
                              void* d_out, int out_size, void* d_ws, size_t ws_size,
                              hipStream_t stream) {
  const float* bi     = (const float*)d_in[0];
  const float* emb    = (const float*)d_in[1];
  const float* eWih   = (const float*)d_in[2];
  const float* eWhh   = (const float*)d_in[3];
  const float* ebih   = (const float*)d_in[4];
  const float* ebhh   = (const float*)d_in[5];
  const float* dWih   = (const float*)d_in[6];
  const float* dWhh   = (const float*)d_in[7];
  const float* dbih   = (const float*)d_in[8];
  const float* dbhh   = (const float*)d_in[9];
  const float* gWq    = (const float*)d_in[10];
  const float* gbq    = (const float*)d_in[11];
  const float* gWref  = (const float*)d_in[12];
  const float* gbref  = (const float*)d_in[13];
  const float* gV     = (const float*)d_in[14];
  const float* pWq    = (const float*)d_in[15];
  const float* pbq    = (const float*)d_in[16];
  const float* pWref  = (const float*)d_in[17];
  const float* pbref  = (const float*)d_in[18];
  const float* pV     = (const float*)d_in[19];
  const float* dstart = (const float*)d_in[20];
  float* ws  = (float*)d_ws;
  float* out = (float*)d_out;

  hipLaunchKernelGGL(prep_kernel, dim3(1280), dim3(256), 0, stream,
                     eWih, eWhh, dWih, dWhh, gWq, gWref, pWq, pWref, ws);
  hipLaunchKernelGGL(pnet_kernel, dim3(512), dim3(256), 0, stream,
                     bi, emb, ebih, ebhh, dbih, dbhh,
                     gbq, gbref, gV, pbq, pbref, pV, dstart, ws, out);
}

// Round 7
// 1336.349 us; speedup vs baseline: 1.5121x; 1.2014x over previous
//
#include <hip/hip_runtime.h>
#include <stdint.h>

// PointerNet fused forward. B=512, S=50, E=H=128.
// 256 blocks x 512 threads (8 waves), 2 batch elements per block.
// AMORTIZED M4 LAYOUT: wave w owns units 16w..16w+15; lane quarter q = l>>4
// owns k-quarter [32q,32q+32); each thread loads each weight float4 ONCE and
// accumulates for BOTH batch elements (halves L2 weight traffic). 4-way
// reductions via shfl_xor(16)+shfl_xor(32). Gate math: quarter pair q>>1
// selects which batch element this lane finalizes (q0 writes be0, q2 be1);
// c persists per-thread for its be. kk order rotated per-quarter so the 4
// concurrent LDS x/h broadcast reads hit distinct banks.
// RG/RP for both elements live in LDS (~111 KB, 1 block/CU, 8 waves/CU).
// Softmax/sampling: wave 0 -> be0, wave 4 -> be1 (parallel).
// Dot products accumulate in f64 (single rounding to f32); elementwise math
// replicates XLA CPU bit patterns (tanh rational poly, logistic-as-tanh,
// sequential softmax sum). Sampling replicates jax.random.categorical with
// THREEFRY PARTITIONABLE mode (JAX >= 0.5 default):
//   fold_in: key' = tf2x32(key, (0, t))
//   split (foldlike): k1 = tf2x32(key', (0, 0))   [both output words]
//   random_bits(32): bits[j] = o0 ^ o1 of tf2x32(k1, (0, j))
// uniform->gumbel exactly as jax._src.random; argmax with first-index ties.
// All cross-lane communication is LDS write -> __syncthreads -> read, or
// register shuffles (round-5 hardening; no unprotected LDS broadcasts).

#define OFF_PIH_E 0
#define OFF_PHH_E 65536
#define OFF_PIH_D 131072
#define OFF_PHH_D 196608
#define OFF_PQG   262144
#define OFF_PRG   278528
#define OFF_PQP   294912
#define OFF_PRP   311296
// ws total: 327680 floats = 1.31 MB

#define RSTR 132   // LDS row stride for RG/RP (16B-aligned)

#define TINYF 1.1754943508222875e-38f

static __device__ __forceinline__ float f_add(float a, float b){ return __fadd_rn(a,b); }
static __device__ __forceinline__ float f_mul(float a, float b){ return __fmul_rn(a,b); }
static __device__ __forceinline__ float f_sub(float a, float b){ return __fsub_rn(a,b); }

static __device__ __forceinline__ double shfl_xor_d(double v, int mask) {
  long long x = __double_as_longlong(v);
  int lo = (int)(x & 0xffffffffll);
  int hi = (int)(x >> 32);
  lo = __shfl_xor(lo, mask);
  hi = __shfl_xor(hi, mask);
  return __longlong_as_double(((long long)hi << 32) | (unsigned long long)(unsigned int)lo);
}
#define RED2(x) { x += shfl_xor_d(x, 16); x += shfl_xor_d(x, 32); }

// XLA CPU tanh: elemental_ir_emitter rational approximation, unfused mul/add.
static __device__ __forceinline__ float tanh_xla(float x) {
  float xc = fminf(fmaxf(x, -7.90531110763549805f), 7.90531110763549805f);
  float x2 = f_mul(xc, xc);
  float p;
  p = -2.76076847742355e-16f;
  p = f_add(f_mul(p, x2),  2.00018790482477e-13f);
  p = f_add(f_mul(p, x2), -8.60467152213735e-11f);
  p = f_add(f_mul(p, x2),  5.12229709037114e-08f);
  p = f_add(f_mul(p, x2),  1.48572235717979e-05f);
  p = f_add(f_mul(p, x2),  6.37261928875436e-04f);
  p = f_add(f_mul(p, x2),  4.89352455891786e-03f);
  p = f_mul(xc, p);
  float q;
  q = 1.19825839466702e-06f;
  q = f_add(f_mul(q, x2), 1.18534705686654e-04f);
  q = f_add(f_mul(q, x2), 2.26843463243900e-03f);
  q = f_add(f_mul(q, x2), 4.89352518554385e-03f);
  float r = __fdiv_rn(p, q);
  return (fabsf(x) < 0.0004f) ? x : r;
}

// XLA logistic expansion: 0.5 + 0.5*tanh(0.5*x)
static __device__ __forceinline__ float sigmoid_xla(float x) {
  return f_add(0.5f, f_mul(0.5f, tanh_xla(f_mul(0.5f, x))));
}

// Threefry-2x32, 20 rounds (JAX key schedule)
static __device__ __forceinline__ void tf2x32(uint32_t k0, uint32_t k1,
                                              uint32_t x0, uint32_t x1,
                                              uint32_t &o0, uint32_t &o1) {
  uint32_t ks2 = k0 ^ k1 ^ 0x1BD11BDAu;
  x0 += k0; x1 += k1;
#define TFR(r) { x0 += x1; x1 = (x1 << (r)) | (x1 >> (32 - (r))); x1 ^= x0; }
  TFR(13) TFR(15) TFR(26) TFR(6)
  x0 += k1;  x1 += ks2 + 1u;
  TFR(17) TFR(29) TFR(16) TFR(24)
  x0 += ks2; x1 += k0 + 2u;
  TFR(13) TFR(15) TFR(26) TFR(6)
  x0 += k0;  x1 += k1 + 3u;
  TFR(17) TFR(29) TFR(16) TFR(24)
  x0 += k1;  x1 += ks2 + 4u;
  TFR(13) TFR(15) TFR(26) TFR(6)
  x0 += ks2; x1 += k0 + 5u;
#undef TFR
  o0 = x0; o1 = x1;
}

// NOTE: parameter names must not collide with float4 member names (.x/.y/.z/.w)
#define ACC4(acc, Wv, Vv) \
  acc = fma((double)(Wv).x, (double)(Vv).x, acc); \
  acc = fma((double)(Wv).y, (double)(Vv).y, acc); \
  acc = fma((double)(Wv).z, (double)(Vv).z, acc); \
  acc = fma((double)(Wv).w, (double)(Vv).w, acc);

// Pack weights: LSTM [512,128] -> P[(k>>2)*2048 + r*4 + (k&3)]
//               attn [128,128] -> P[(k>>2)*512  + o*4 + (k&3)]
__global__ void prep_kernel(const float* __restrict__ eWih, const float* __restrict__ eWhh,
                            const float* __restrict__ dWih, const float* __restrict__ dWhh,
                            const float* __restrict__ gWq,  const float* __restrict__ gWref,
                            const float* __restrict__ pWq,  const float* __restrict__ pWref,
                            float* __restrict__ ws) {
  int id = blockIdx.x * blockDim.x + threadIdx.x;
  if (id < 262144) {
    int m = id >> 16, e = id & 65535;
    const float* src = (m == 0) ? eWih : (m == 1) ? eWhh : (m == 2) ? dWih : dWhh;
    int r = e >> 7, k = e & 127;
    ws[m * 65536 + (k >> 2) * 2048 + r * 4 + (k & 3)] = src[e];
  } else if (id < 327680) {
    int a = id - 262144;
    int m = a >> 14, e = a & 16383;
    const float* src = (m == 0) ? gWq : (m == 1) ? gWref : (m == 2) ? pWq : pWref;
    int o = e >> 7, k = e & 127;
    ws[262144 + m * 16384 + (k >> 2) * 512 + o * 4 + (k & 3)] = src[e];
  }
}

// Quarter-k LSTM step for BOTH batch elements; weights loaded once.
// Returns h_new for be = besel (q0/q1 lanes -> be0, q2/q3 -> be1); c is this
// lane's cell state for its besel.
static __device__ __forceinline__ float lstm_step4(
    int u, int q, int besel,
    const float4* __restrict__ PIH, const float4* __restrict__ PHH,
    const float* __restrict__ bih, const float* __restrict__ bhh,
    const float4* __restrict__ xA, const float4* __restrict__ hA,
    const float4* __restrict__ xB, const float4* __restrict__ hB,
    float &c)
{
  double diA=0,dfA=0,dgA=0,ddA=0, eiA=0,efA=0,egA=0,eoA=0;
  double diB=0,dfB=0,dgB=0,ddB=0, eiB=0,efB=0,egB=0,eoB=0;
  const int kb = q * 8;
#pragma unroll 4
  for (int kk = 0; kk < 8; kk++) {
    int k4 = kb + ((kk + 2 * q) & 7);     // per-quarter rotation: bank-spread
    float4 w0 = PIH[k4 * 512 + u];
    float4 w1 = PIH[k4 * 512 + u + 128];
    float4 w2 = PIH[k4 * 512 + u + 256];
    float4 w3 = PIH[k4 * 512 + u + 384];
    float4 xvA = xA[k4]; float4 xvB = xB[k4];
    ACC4(diA, w0, xvA) ACC4(dfA, w1, xvA) ACC4(dgA, w2, xvA) ACC4(ddA, w3, xvA)
    ACC4(diB, w0, xvB) ACC4(dfB, w1, xvB) ACC4(dgB, w2, xvB) ACC4(ddB, w3, xvB)
    float4 v0 = PHH[k4 * 512 + u];
    float4 v1 = PHH[k4 * 512 + u + 128];
    float4 v2 = PHH[k4 * 512 + u + 256];
    float4 v3 = PHH[k4 * 512 + u + 384];
    float4 hvA = hA[k4]; float4 hvB = hB[k4];
    ACC4(eiA, v0, hvA) ACC4(efA, v1, hvA) ACC4(egA, v2, hvA) ACC4(eoA, v3, hvA)
    ACC4(eiB, v0, hvB) ACC4(efB, v1, hvB) ACC4(egB, v2, hvB) ACC4(eoB, v3, hvB)
  }
  RED2(diA) RED2(dfA) RED2(dgA) RED2(ddA)
  RED2(eiA) RED2(efA) RED2(egA) RED2(eoA)
  RED2(diB) RED2(dfB) RED2(dgB) RED2(ddB)
  RED2(eiB) RED2(efB) RED2(egB) RED2(eoB)
  double di = besel ? diB : diA, df = besel ? dfB : dfA;
  double dg = besel ? dgB : dgA, dd = besel ? ddB : ddA;
  double ei = besel ? eiB : eiA, ef = besel ? efB : efA;
  double eg = besel ? egB : egA, eo = besel ? eoB : eoA;
  // ((x@Wih^T + bih) + h@Whh^T) + bhh  -- XLA add tree order
  float gi = f_add(f_add(f_add((float)di, bih[u      ]), (float)ei), bhh[u      ]);
  float gf = f_add(f_add(f_add((float)df, bih[u + 128]), (float)ef), bhh[u + 128]);
  float gg = f_add(f_add(f_add((float)dg, bih[u + 256]), (float)eg), bhh[u + 256]);
  float go = f_add(f_add(f_add((float)dd, bih[u + 384]), (float)eo), bhh[u + 384]);
  float I = sigmoid_xla(gi);
  float F = sigmoid_xla(gf);
  float G = tanh_xla(gg);
  float O = sigmoid_xla(go);
  c = f_add(f_mul(F, c), f_mul(I, G));
  return f_mul(O, tanh_xla(c));
}

// Quarter-k 128x128 matvec for BOTH batch elements (weights loaded once).
// Returns (float)(selected dot) + bias[u].
static __device__ __forceinline__ float mv_step4(
    int u, int q, int besel,
    const float4* __restrict__ PW, const float* __restrict__ bias,
    const float4* __restrict__ xA, const float4* __restrict__ xB)
{
  double aA = 0, aB = 0;
  const int kb = q * 8;
#pragma unroll 4
  for (int kk = 0; kk < 8; kk++) {
    int k4 = kb + ((kk + 2 * q) & 7);
    float4 wv = PW[k4 * 128 + u];
    float4 xvA = xA[k4]; float4 xvB = xB[k4];
    ACC4(aA, wv, xvA) ACC4(aB, wv, xvB)
  }
  RED2(aA) RED2(aB)
  double tot = besel ? aB : aA;
  return f_add((float)tot, bias[u]);
}

__global__ void __launch_bounds__(512)
pnet_kernel(const float* __restrict__ bi, const float* __restrict__ emb,
            const float* __restrict__ ebih, const float* __restrict__ ebhh,
            const float* __restrict__ dbih, const float* __restrict__ dbhh,
            const float* __restrict__ gbq, const float* __restrict__ gbref, const float* __restrict__ gV,
            const float* __restrict__ pbq, const float* __restrict__ pbref, const float* __restrict__ pV,
            const float* __restrict__ dstart,
            float* __restrict__ ws, float* __restrict__ out)
{
  __shared__ __align__(16) float sRG[2][50 * RSTR];   // 52.8 KB
  __shared__ __align__(16) float sRP[2][50 * RSTR];   // 52.8 KB
  __shared__ __align__(16) float sh_x[2][128];
  __shared__ __align__(16) float sh_h[2][128];
  __shared__ __align__(16) float sh_q[2][128];
  __shared__ __align__(16) float sh_q2[2][128];
  __shared__ float sh_att[2][64];
  __shared__ float sh_w[2][64];
  __shared__ unsigned long long sh_msk[2];
  __shared__ int sh_idx[2];

  const int tid   = threadIdx.x;            // 0..511
  const int l     = tid & 63;               // lane
  const int w     = tid >> 6;               // wave 0..7
  const int u     = w * 16 + (l & 15);      // unit 0..127
  const int q     = l >> 4;                 // k-quarter 0..3
  const int besel = q >> 1;                 // which be this lane finalizes
  const bool wq0  = (q & 1) == 0;           // writer lanes (q0 -> be0, q2 -> be1)
  const int gb2   = blockIdx.x * 2;         // first batch element of block

  const float4* PIH_E = (const float4*)(ws + OFF_PIH_E);
  const float4* PHH_E = (const float4*)(ws + OFF_PHH_E);
  const float4* PIH_D = (const float4*)(ws + OFF_PIH_D);
  const float4* PHH_D = (const float4*)(ws + OFF_PHH_D);
  const float4* PQG = (const float4*)(ws + OFF_PQG);
  const float4* PRG = (const float4*)(ws + OFF_PRG);
  const float4* PQP = (const float4*)(ws + OFF_PQP);
  const float4* PRP = (const float4*)(ws + OFF_PRP);

  const float NEG_INF = -__builtin_inff();

  if (tid < 128) { sh_h[0][tid] = 0.0f; sh_h[1][tid] = 0.0f; }
  if (tid == 0) { sh_msk[0] = 0ull; sh_msk[1] = 0ull; }
  float c_st = 0.0f;
  __syncthreads();

  // ---------------- encoder + fused ref projections ----------------
  for (int t = 0; t < 50; t++) {
    if (wq0) {
      float x0 = bi[(gb2 + besel) * 100 + t];
      float x1 = bi[(gb2 + besel) * 100 + 50 + t];
      sh_x[besel][u] = __fmaf_rn(x1, emb[128 + u], f_mul(x0, emb[u]));
    }
    __syncthreads();
    float hn = lstm_step4(u, q, besel, PIH_E, PHH_E, ebih, ebhh,
                          (const float4*)sh_x[0], (const float4*)sh_h[0],
                          (const float4*)sh_x[1], (const float4*)sh_h[1], c_st);
    __syncthreads();
    if (wq0) sh_h[besel][u] = hn;
    __syncthreads();
    // rg/rp[t][u] (Conv1d k=1 fused), both be, weights loaded once
    {
      double agA = 0, apA = 0, agB = 0, apB = 0;
      const int kb = q * 8;
      const float4* hA4 = (const float4*)sh_h[0];
      const float4* hB4 = (const float4*)sh_h[1];
#pragma unroll 4
      for (int kk = 0; kk < 8; kk++) {
        int k4 = kb + ((kk + 2 * q) & 7);
        float4 wg = PRG[k4 * 128 + u];
        float4 wp = PRP[k4 * 128 + u];
        float4 xvA = hA4[k4]; float4 xvB = hB4[k4];
        ACC4(agA, wg, xvA) ACC4(agB, wg, xvB)
        ACC4(apA, wp, xvA) ACC4(apB, wp, xvB)
      }
      RED2(agA) RED2(agB) RED2(apA) RED2(apB)
      if (wq0) {
        sRG[besel][t * RSTR + u] = f_add((float)(besel ? agB : agA), gbref[u]);
        sRP[besel][t * RSTR + u] = f_add((float)(besel ? apB : apA), pbref[u]);
      }
    }
    // loop-top sh_x write guarded by the barrier right after it
  }
  if (wq0) sh_x[besel][u] = dstart[u];   // decoder initial input
  __syncthreads();

  // ---------------- decoder ----------------
  for (int t = 0; t < 50; t++) {
    // partitionable threefry:
    //   fk = fold_in(key(42), t) = tf((0,42), (0,t))
    //   k1 = split(fk, 2)[0]     = tf(fk, (0,0))   [foldlike: both words]
    uint32_t f0, f1, k1a, k1b;
    tf2x32(0u, 42u, 0u, (uint32_t)t, f0, f1);
    tf2x32(f0, f1, 0u, 0u, k1a, k1b);

    float hn = lstm_step4(u, q, besel, PIH_D, PHH_D, dbih, dbhh,
                          (const float4*)sh_x[0], (const float4*)sh_h[0],
                          (const float4*)sh_x[1], (const float4*)sh_h[1], c_st);
    __syncthreads();                                  // B1
    if (wq0) sh_h[besel][u] = hn;
    __syncthreads();                                  // B2

    // glimpse query: qg = Wq_g @ h + bq_g (both be)
    {
      float qv = mv_step4(u, q, besel, PQG, gbq,
                          (const float4*)sh_h[0], (const float4*)sh_h[1]);
      if (wq0) sh_q[besel][u] = qv;
    }
    __syncthreads();                                  // B3

    // glimpse logits: lg[s] = sum_h V[h]*tanh(qg[h]+ref_g[s][h]); 4 lanes/row
    {
      double acc = 0.0;
      const int r = tid & 255;
      const int be = tid >> 8;
      const int s = r >> 2;
      const int hf = (r & 3) * 32;
      if (r < 200) {
        const float4* rr = (const float4*)(&sRG[be][s * RSTR + hf]);
        const float4* qq = (const float4*)(&sh_q[be][hf]);
        const float4* vvp = (const float4*)(gV + hf);
#pragma unroll 2
        for (int k4 = 0; k4 < 8; k4++) {
          float4 rv = rr[k4];
          float4 qv = qq[k4];
          float4 gvv = vvp[k4];
          acc = fma((double)gvv.x, (double)tanh_xla(f_add(qv.x, rv.x)), acc);
          acc = fma((double)gvv.y, (double)tanh_xla(f_add(qv.y, rv.y)), acc);
          acc = fma((double)gvv.z, (double)tanh_xla(f_add(qv.z, rv.z)), acc);
          acc = fma((double)gvv.w, (double)tanh_xla(f_add(qv.w, rv.w)), acc);
        }
      }
      double tot = acc + shfl_xor_d(acc, 1);
      tot = tot + shfl_xor_d(tot, 2);
      if (r < 200 && (r & 3) == 0) {
        float lg = (float)tot;
        sh_att[be][s] = ((sh_msk[be] >> s) & 1ull) ? NEG_INF : lg;
      }
      if (r >= 200 && r < 214) sh_att[be][r - 150] = NEG_INF;   // pad 50..63
    }
    __syncthreads();                                  // B4

    // glimpse softmax: wave 0 -> be0, wave 4 -> be1
    if ((w & 3) == 0) {
      const int be = w >> 2;
      float v = sh_att[be][l];
      float m = v;
      for (int off = 32; off > 0; off >>= 1) m = fmaxf(m, __shfl_xor(m, off));
      float e = (l < 50) ? expf(f_sub(v, m)) : 0.0f;
      float ss = 0.0f;
      for (int s2 = 0; s2 < 50; s2++) ss = f_add(ss, __shfl(e, s2));
      float wv = __fdiv_rn(e, ss);
      sh_w[be][l] = (l < 50) ? wv : 0.0f;
    }
    __syncthreads();                                  // B5

    // q2 = sum_s w[s]*ref_g[s][:]; s-halves by (q&1), combine xor16; both be
    {
      double aA = 0, aB = 0;
      const int s0 = (q & 1) * 25;
      for (int s2 = s0; s2 < s0 + 25; s2++) {
        float wvA = sh_w[0][s2];
        float wvB = sh_w[1][s2];
        aA = fma((double)sRG[0][s2 * RSTR + u], (double)wvA, aA);
        aB = fma((double)sRG[1][s2 * RSTR + u], (double)wvB, aB);
      }
      aA += shfl_xor_d(aA, 16);
      aB += shfl_xor_d(aB, 16);
      if (wq0) sh_q2[besel][u] = (float)(besel ? aB : aA);
    }
    __syncthreads();                                  // B6

    // pointer query: qp = Wq_p @ q2 + bq_p (both be)
    {
      float qv = mv_step4(u, q, besel, PQP, pbq,
                          (const float4*)sh_q2[0], (const float4*)sh_q2[1]);
      if (wq0) sh_q[besel][u] = qv;
    }
    __syncthreads();                                  // B7

    // pointer logits + 10*tanh + mask; 4 lanes/row
    {
      double acc = 0.0;
      const int r = tid & 255;
      const int be = tid >> 8;
      const int s = r >> 2;
      const int hf = (r & 3) * 32;
      if (r < 200) {
        const float4* rr = (const float4*)(&sRP[be][s * RSTR + hf]);
        const float4* qq = (const float4*)(&sh_q[be][hf]);
        const float4* vvp = (const float4*)(pV + hf);
#pragma unroll 2
        for (int k4 = 0; k4 < 8; k4++) {
          float4 rv = rr[k4];
          float4 qv = qq[k4];
          float4 pvv = vvp[k4];
          acc = fma((double)pvv.x, (double)tanh_xla(f_add(qv.x, rv.x)), acc);
          acc = fma((double)pvv.y, (double)tanh_xla(f_add(qv.y, rv.y)), acc);
          acc = fma((double)pvv.z, (double)tanh_xla(f_add(qv.z, rv.z)), acc);
          acc = fma((double)pvv.w, (double)tanh_xla(f_add(qv.w, rv.w)), acc);
        }
      }
      double tot = acc + shfl_xor_d(acc, 1);
      tot = tot + shfl_xor_d(tot, 2);
      if (r < 200 && (r & 3) == 0) {
        float lp = (float)tot;
        lp = f_mul(10.0f, tanh_xla(lp));
        sh_att[be][s] = ((sh_msk[be] >> s) & 1ull) ? NEG_INF : lp;
      }
      if (r >= 200 && r < 214) sh_att[be][r - 150] = NEG_INF;
    }
    __syncthreads();                                  // B8

    // probs output + gumbel sampling: wave 0 -> be0, wave 4 -> be1
    if ((w & 3) == 0) {
      const int be = w >> 2;
      float v = sh_att[be][l];
      float m = v;
      for (int off = 32; off > 0; off >>= 1) m = fmaxf(m, __shfl_xor(m, off));
      float e = (l < 50) ? expf(f_sub(v, m)) : 0.0f;
      float ss = 0.0f;
      for (int s2 = 0; s2 < 50; s2++) ss = f_add(ss, __shfl(e, s2));
      if (l < 50) out[t * 25600 + (gb2 + be) * 50 + l] = __fdiv_rn(e, ss);

      float val = NEG_INF;
      int ii = l;
      if (l < 50) {
        int j = (gb2 + be) * 50 + l;       // flat index into (B,S) gumbel draw
        // partitionable random_bits(32): bits[j] = o0 ^ o1 of tf(k1, (0, j))
        uint32_t b0, b1;
        tf2x32(k1a, k1b, 0u, (uint32_t)j, b0, b1);
        uint32_t bits = b0 ^ b1;
        float fl = __uint_as_float((bits >> 9) | 0x3f800000u) - 1.0f;  // [0,1)
        float uu = f_add(fl, TINYF);
        uu = fmaxf(TINYF, uu);
        float gum = -logf(-logf(uu));
        val = f_add(v, gum);               // -inf stays -inf for masked
      }
      // argmax, first-index tiebreak (jnp.argmax semantics)
      for (int off = 32; off > 0; off >>= 1) {
        float ov = __shfl_down(val, off);
        int   oi = __shfl_down(ii, off);
        if (ov > val || (ov == val && oi < ii)) { val = ov; ii = oi; }
      }
      if (l == 0) {
        sh_idx[be] = ii;
        sh_msk[be] |= (1ull << ii);        // masks step t+1 onward
        out[1280000 + t * 512 + gb2 + be] = (float)ii;
      }
    }
    __syncthreads();                                  // B9

    // next decoder input: embedded[b, idx]
    if (wq0) {
      int idx = sh_idx[besel];
      float x0 = bi[(gb2 + besel) * 100 + idx];
      float x1 = bi[(gb2 + besel) * 100 + 50 + idx];
      sh_x[besel][u] = __fmaf_rn(x1, emb[128 + u], f_mul(x0, emb[u]));
    }
    __syncthreads();                                  // B10
  }
}

extern "C" void kernel_launch(void* const* d_in, const int* in_sizes, int n_in,
                              void* d_out, int out_size, void* d_ws, size_t ws_size,
                              hipStream_t stream) {
  const float* bi     = (const float*)d_in[0];
  const float* emb    = (const float*)d_in[1];
  const float* eWih   = (const float*)d_in[2];
  const float* eWhh   = (const float*)d_in[3];
  const float* ebih   = (const float*)d_in[4];
  const float* ebhh   = (const float*)d_in[5];
  const float* dWih   = (const float*)d_in[6];
  const float* dWhh   = (const float*)d_in[7];
  const float* dbih   = (const float*)d_in[8];
  const float* dbhh   = (const float*)d_in[9];
  const float* gWq    = (const float*)d_in[10];
  const float* gbq    = (const float*)d_in[11];
  const float* gWref  = (const float*)d_in[12];
  const float* gbref  = (const float*)d_in[13];
  const float* gV     = (const float*)d_in[14];
  const float* pWq    = (const float*)d_in[15];
  const float* pbq    = (const float*)d_in[16];
  const float* pWref  = (const float*)d_in[17];
  const float* pbref  = (const float*)d_in[18];
  const float* pV     = (const float*)d_in[19];
  const float* dstart = (const float*)d_in[20];
  float* ws  = (float*)d_ws;
  float* out = (float*)d_out;

  hipLaunchKernelGGL(prep_kernel, dim3(1280), dim3(256), 0, stream,
                     eWih, eWhh, dWih, dWhh, gWq, gWref, pWq, pWref, ws);
  hipLaunchKernelGGL(pnet_kernel, dim3(256), dim3(512), 0, stream,
                     bi, emb, ebih, ebhh, dbih, dbhh,
                     gbq, gbref, gV, pbq, pbref, pV, dstart, ws, out);
}